// Round 1
// baseline (212.427 us; speedup 1.0000x reference)
//
#include <hip/hip_runtime.h>

#define NB 128
#define CC 1024
#define HWP 196
#define HH 14
#define OO 256

typedef unsigned short ushort_t;
typedef __attribute__((ext_vector_type(8))) short short8;
typedef __attribute__((ext_vector_type(4))) float float4v;

__device__ __forceinline__ ushort_t f2bf(float v) {
  union { float f; unsigned int u; } c; c.f = v;
  unsigned int u = c.u;
  unsigned int r = (u + 0x7FFFu + ((u >> 16) & 1u)) >> 16;   // RNE
  return (ushort_t)r;
}

// K1: partial channel-sum: partial[n][cg][p] = sum_{c in group} x[n][c][p]
__global__ __launch_bounds__(256) void k_reduce(const float* __restrict__ x,
                                                float* __restrict__ partial) {
  int n = blockIdx.x, cg = blockIdx.y;
  int p = threadIdx.x;
  if (p >= HWP) return;
  const float* base = x + ((size_t)n * CC + (size_t)cg * 128) * HWP + p;
  float s = 0.f;
  #pragma unroll 8
  for (int c = 0; c < 128; ++c) s += base[(size_t)c * HWP];
  partial[(n * 8 + cg) * HWP + p] = s;
}

// K2: exact stable argsort(-fre) rank selection; writes scene + rows/cols outputs
__global__ __launch_bounds__(256) void k_select(const float* __restrict__ partial,
                                                int* __restrict__ scene,
                                                float* __restrict__ out) {
  int n = blockIdx.x, t = threadIdx.x;
  __shared__ float fre[HWP];
  __shared__ int sc[32];
  if (t < HWP) {
    float s = 0.f;
    #pragma unroll
    for (int g = 0; g < 8; ++g) s += partial[(n * 8 + g) * HWP + t];
    fre[t] = s;
  }
  __syncthreads();
  if (t < HWP) {
    float v = fre[t];
    int rank = 0;
    for (int q = 0; q < HWP; ++q) {
      float u = fre[q];
      rank += ((u > v) || (u == v && q < t)) ? 1 : 0;
    }
    if (rank < 16) sc[rank] = t;                       // maxK: ranks 0..15
    else if (rank >= 89 && rank < 105) sc[rank - 73] = t;  // medK: ranks 89..104
  }
  __syncthreads();
  if (t < 32) {
    int p = sc[t];
    scene[n * 32 + t] = p;
    out[2 * NB * 4096 + n * 32 + t] = (float)(p / HH);            // rows
    out[2 * NB * 4096 + NB * 32 + n * 32 + t] = (float)(p % HH);  // cols
  }
}

// K3: cast weights to bf16; wb[z][o][k] layout == w row-major (no transpose:
// this IS the MFMA B-operand-friendly layout, contiguous in k).
__global__ __launch_bounds__(256) void k_convw(const float* __restrict__ wmax,
                                               const float* __restrict__ wmed,
                                               ushort_t* __restrict__ wb) {
  int idx = blockIdx.x * 256 + threadIdx.x;
  int z = idx >> 18;                 // 262144 elements per z
  int r = idx & (OO * CC - 1);
  const float* w = z ? wmed : wmax;
  wb[idx] = f2bf(w[r]);
}

// K4: fused gather + bf16 MFMA GEMM + BN + ReLU + Lnorm apply.
// One block per (n, z). 4 waves; wave w owns output cols [w*64, w*64+64).
__global__ __launch_bounds__(256) void k_main(
    const float* __restrict__ x, const ushort_t* __restrict__ wb,
    const float* __restrict__ g_max, const float* __restrict__ b_max,
    const float* __restrict__ m_max, const float* __restrict__ v_max,
    const float* __restrict__ g_med, const float* __restrict__ b_med,
    const float* __restrict__ m_med, const float* __restrict__ v_med,
    const int* __restrict__ scene, float* __restrict__ out) {
  constexpr int AP = 1032;               // padded A row (ushorts): 2064B stride, 16B-aligned, 2-way-free banks
  __shared__ ushort_t A_sh[16 * AP];     // ~33 KB: A[j][k] bf16
  __shared__ float Lsh[16][17];
  __shared__ float dinv[16];
  __shared__ int s_sh[16];
  __shared__ float y_sh[16][257];        // ~16.4 KB: post-BN-relu x, scaled by dinv_j

  const int n = blockIdx.x;
  const int z = blockIdx.y;
  const int t = threadIdx.x;

  if (t < 16) s_sh[t] = scene[n * 32 + z * 16 + t];
  __syncthreads();

  // gather A (16 x 1024) from fpam (L3-resident after k_reduce), convert to bf16
  {
    const int j = t & 15;
    const int kg = t >> 4;             // 16 k-groups of 64
    const int sj = s_sh[j];
    const float* xb = x + (size_t)n * (CC * HWP) + sj;
    ushort_t* arow = &A_sh[j * AP];
    #pragma unroll 8
    for (int u = 0; u < 64; ++u) {
      int k = kg * 64 + u;
      arow[k] = f2bf(xb[(size_t)k * HWP]);
    }
  }
  // L matrix: A_ij = 1/(1+dist)
  {
    const int i = t >> 4, j = t & 15;
    int pi = s_sh[i], pj = s_sh[j];
    float dr = (float)(pi / HH - pj / HH);
    float dc = (float)(pi % HH - pj % HH);
    Lsh[i][j] = 1.0f / (1.0f + sqrtf(dr * dr + dc * dc));
  }
  __syncthreads();
  if (t < 16) {
    float s = 0.f;
    #pragma unroll
    for (int j = 0; j < 16; ++j) s += Lsh[t][j];
    dinv[t] = rsqrtf(s);
  }

  const int w = t >> 6;
  const int l = t & 63;
  const int m = l & 15;                  // A-row / C-col / B-col index
  const int quad = l >> 4;

  const ushort_t* Arow = &A_sh[m * AP + quad * 8];
  const ushort_t* B0 = wb + (size_t)z * (OO * CC) + (size_t)(w * 64 + m) * CC + quad * 8;

  float4v acc0 = {0.f, 0.f, 0.f, 0.f};
  float4v acc1 = acc0, acc2 = acc0, acc3 = acc0;

  __syncthreads();   // dinv visible; A_sh already synced above

  #pragma unroll 2
  for (int k0 = 0; k0 < CC; k0 += 32) {
    short8 a  = *reinterpret_cast<const short8*>(Arow + k0);
    short8 b0 = *reinterpret_cast<const short8*>(B0 + k0);
    short8 b1 = *reinterpret_cast<const short8*>(B0 + 16 * CC + k0);
    short8 b2 = *reinterpret_cast<const short8*>(B0 + 32 * CC + k0);
    short8 b3 = *reinterpret_cast<const short8*>(B0 + 48 * CC + k0);
    acc0 = __builtin_amdgcn_mfma_f32_16x16x32_bf16(a, b0, acc0, 0, 0, 0);
    acc1 = __builtin_amdgcn_mfma_f32_16x16x32_bf16(a, b1, acc1, 0, 0, 0);
    acc2 = __builtin_amdgcn_mfma_f32_16x16x32_bf16(a, b2, acc2, 0, 0, 0);
    acc3 = __builtin_amdgcn_mfma_f32_16x16x32_bf16(a, b3, acc3, 0, 0, 0);
  }

  const float* gp = z ? g_med : g_max;
  const float* bp = z ? b_med : b_max;
  const float* mp = z ? m_med : m_max;
  const float* vp = z ? v_med : v_max;

  // epilogue: BN + ReLU, scatter C-layout (col=lane&15, row=quad*4+reg) to LDS
  #pragma unroll
  for (int tt = 0; tt < 4; ++tt) {
    float4v av = (tt == 0) ? acc0 : (tt == 1) ? acc1 : (tt == 2) ? acc2 : acc3;
    int o = w * 64 + tt * 16 + m;
    float sc = gp[o] * rsqrtf(vp[o] + 1e-5f);
    float sh = bp[o] - mp[o] * sc;
    #pragma unroll
    for (int r = 0; r < 4; ++r) {
      int j = quad * 4 + r;
      float y = av[r] * sc + sh;
      y = fmaxf(y, 0.f);
      y_sh[j][o] = y * dinv[j];         // fold dinv_j here
    }
  }
  __syncthreads();

  // final: out[n,z,i,o] = dinv_i * sum_j L[i][j] * (dinv_j * y[j][o]); thread = o
  float yp[16];
  #pragma unroll
  for (int j = 0; j < 16; ++j) yp[j] = y_sh[j][t];
  float* ob = out + (size_t)z * (NB * 4096) + (size_t)n * 4096 + t;
  #pragma unroll
  for (int i = 0; i < 16; ++i) {
    float s = 0.f;
    #pragma unroll
    for (int j = 0; j < 16; ++j) s = fmaf(Lsh[i][j], yp[j], s);
    ob[(size_t)i * OO] = s * dinv[i];
  }
}

extern "C" void kernel_launch(void* const* d_in, const int* in_sizes, int n_in,
                              void* d_out, int out_size, void* d_ws, size_t ws_size,
                              hipStream_t stream) {
  const float* x     = (const float*)d_in[0];
  // d_in[1] = resnet_output: unused by the reference
  const float* w_max = (const float*)d_in[2];
  const float* g_max = (const float*)d_in[3];
  const float* b_max = (const float*)d_in[4];
  const float* m_max = (const float*)d_in[5];
  const float* v_max = (const float*)d_in[6];
  const float* w_med = (const float*)d_in[7];
  const float* g_med = (const float*)d_in[8];
  const float* b_med = (const float*)d_in[9];
  const float* m_med = (const float*)d_in[10];
  const float* v_med = (const float*)d_in[11];
  float* out = (float*)d_out;

  float* ws_f = (float*)d_ws;
  float* partial  = ws_f;                        // 128*8*196 = 200704 floats
  int* scene      = (int*)(ws_f + 200704);       // 4096 ints
  ushort_t* wb    = (ushort_t*)(ws_f + 204800);  // 2*256*1024 ushorts (1 MB), 16B-aligned

  k_reduce<<<dim3(NB, 8), 256, 0, stream>>>(x, partial);
  k_select<<<dim3(NB), 256, 0, stream>>>(partial, scene, out);
  k_convw<<<dim3((2 * OO * CC) / 256), 256, 0, stream>>>(w_max, w_med, wb);
  k_main<<<dim3(NB, 2), 256, 0, stream>>>(x, wb, g_max, b_max, m_max, v_max,
                                          g_med, b_med, m_med, v_med, scene, out);
}